// Round 1
// baseline (497.070 us; speedup 1.0000x reference)
//
#include <hip/hip_runtime.h>

#define WIN 7
#define H 320
#define W 320
#define OH 314
#define OW 314
#define TILE 32
#define ITILE 38   // TILE + WIN - 1
#define NIMG 256   // 32 * 8

__global__ __launch_bounds__(256) void ssim_tile_kernel(
    const float* __restrict__ X, const float* __restrict__ Y,
    const float* __restrict__ dr_p, const float* __restrict__ w_p,
    double* __restrict__ accum)
{
    __shared__ float sX[ITILE][40];   // padded stride 40
    __shared__ float sY[ITILE][40];
    __shared__ float hs0[ITILE][33];  // sum x
    __shared__ float hs1[ITILE][33];  // sum y
    __shared__ float hs2[ITILE][33];  // sum x*x
    __shared__ float hs3[ITILE][33];  // sum y*y
    __shared__ float hs4[ITILE][33];  // sum x*y

    const int t   = threadIdx.x;
    const int gx0 = blockIdx.x * TILE;
    const int gy0 = blockIdx.y * TILE;
    const int img = blockIdx.z;
    const float* __restrict__ Xb = X + (size_t)img * (H * W);
    const float* __restrict__ Yb = Y + (size_t)img * (H * W);

    // ---- stage 38x38 input tiles (zero-fill out of range; those feed only
    // invalid output pixels which are skipped) ----
    for (int idx = t; idx < ITILE * ITILE; idx += 256) {
        int r = idx / ITILE;
        int c = idx - r * ITILE;
        int gr = gy0 + r, gc = gx0 + c;
        float xv = 0.f, yv = 0.f;
        if (gr < H && gc < W) {
            xv = Xb[gr * W + gc];
            yv = Yb[gr * W + gc];
        }
        sX[r][c] = xv;
        sY[r][c] = yv;
    }
    __syncthreads();

    // ---- horizontal 7-sums of the 5 moments: 38 rows x 32 out-cols ----
    for (int idx = t; idx < ITILE * TILE; idx += 256) {
        int r = idx >> 5;
        int c = idx & 31;
        float sx = 0.f, sy = 0.f, sxx = 0.f, syy = 0.f, sxy = 0.f;
#pragma unroll
        for (int k = 0; k < WIN; ++k) {
            float x = sX[r][c + k];
            float y = sY[r][c + k];
            sx += x; sy += y;
            sxx += x * x; syy += y * y; sxy += x * y;
        }
        hs0[r][c] = sx;  hs1[r][c] = sy;
        hs2[r][c] = sxx; hs3[r][c] = syy; hs4[r][c] = sxy;
    }
    __syncthreads();

    const float dr = dr_p[0];
    const float w0 = w_p[0];              // uniform 1/49 weight
    const float C1 = (0.01f * dr) * (0.01f * dr);
    const float C2 = (0.03f * dr) * (0.03f * dr);
    const float COV_NORM = 49.0f / 48.0f;

    float partial = 0.f;
    const int c  = t & 31;
    const int r0 = t >> 5;                // 0..7
#pragma unroll
    for (int i = 0; i < 4; ++i) {
        int r  = r0 + 8 * i;              // 0..31
        int oy = gy0 + r, ox = gx0 + c;
        float sx = 0.f, sy = 0.f, sxx = 0.f, syy = 0.f, sxy = 0.f;
#pragma unroll
        for (int k = 0; k < WIN; ++k) {
            sx  += hs0[r + k][c];
            sy  += hs1[r + k][c];
            sxx += hs2[r + k][c];
            syy += hs3[r + k][c];
            sxy += hs4[r + k][c];
        }
        if (oy < OH && ox < OW) {
            float ux  = sx  * w0, uy  = sy  * w0;
            float uxx = sxx * w0, uyy = syy * w0, uxy = sxy * w0;
            float vx  = COV_NORM * (uxx - ux * ux);
            float vy  = COV_NORM * (uyy - uy * uy);
            float vxy = COV_NORM * (uxy - ux * uy);
            float A1 = 2.f * ux * uy + C1;
            float A2 = 2.f * vxy + C2;
            float B1 = ux * ux + uy * uy + C1;
            float B2 = vx + vy + C2;
            float S  = (A1 * A2) / (B1 * B2 + 1e-8f);
            partial += S;
        }
    }

    // ---- reduce: wave64 shuffle, then cross-wave via LDS ----
#pragma unroll
    for (int off = 32; off > 0; off >>= 1)
        partial += __shfl_down(partial, off, 64);

    __shared__ float wsum[4];
    const int wave = t >> 6;
    const int lane = t & 63;
    if (lane == 0) wsum[wave] = partial;
    __syncthreads();
    if (t == 0) {
        float s = wsum[0] + wsum[1] + wsum[2] + wsum[3];
        atomicAdd(accum, (double)s);
    }
}

__global__ void ssim_finalize_kernel(const double* __restrict__ accum,
                                     float* __restrict__ out)
{
    const double cnt = (double)(32 * 8) * (double)(OH * OW);
    out[0] = 1.0f - (float)(accum[0] / cnt);
}

extern "C" void kernel_launch(void* const* d_in, const int* in_sizes, int n_in,
                              void* d_out, int out_size, void* d_ws, size_t ws_size,
                              hipStream_t stream) {
    const float* X  = (const float*)d_in[0];
    const float* Y  = (const float*)d_in[1];
    const float* dr = (const float*)d_in[2];
    const float* w  = (const float*)d_in[3];
    double* accum   = (double*)d_ws;
    float* out      = (float*)d_out;

    hipMemsetAsync(accum, 0, sizeof(double), stream);

    dim3 grid((OW + TILE - 1) / TILE, (OH + TILE - 1) / TILE, NIMG); // 10,10,256
    ssim_tile_kernel<<<grid, 256, 0, stream>>>(X, Y, dr, w, accum);
    ssim_finalize_kernel<<<1, 1, 0, stream>>>(accum, out);
}

// Round 3
// 268.363 us; speedup vs baseline: 1.8522x; 1.8522x over previous
//
#include <hip/hip_runtime.h>

#define H 320
#define W 320
#define OH 314
#define OW 314
#define NIMG 256       // 32 batch * 8 channels
#define STRIP_OUT 42   // output rows per wave-strip (multiple of 7)
#define NSTRIP 8       // 8*42 = 336 >= 314
#define NGRP 3         // column groups; each wave covers 122 output cols
#define GRPW 122

__device__ __forceinline__ float ssim_val(float sxs, float sys, float sxxs,
                                          float syys, float sxys,
                                          float w0, float C1, float C2) {
    const float COV = 49.0f / 48.0f;
    float ux  = sxs  * w0, uy  = sys  * w0;
    float uxx = sxxs * w0, uyy = syys * w0, uxy = sxys * w0;
    float vx  = COV * (uxx - ux * ux);
    float vy  = COV * (uyy - uy * uy);
    float vxy = COV * (uxy - ux * uy);
    float A1 = 2.f * ux * uy + C1;
    float A2 = 2.f * vxy + C2;
    float B1 = ux * ux + uy * uy + C1;
    float B2 = vx + vy + C2;
    float den = B1 * B2 + 1e-8f;
    float inv = __builtin_amdgcn_rcpf(den);
    inv = inv * (2.f - den * inv);          // one Newton step
    return (A1 * A2) * inv;
}

// horizontal 7-window sums from per-lane float2 vertical sums.
// lane l holds cols (2l, 2l+1) of moment v2. e = window at even col, o = odd.
#define HSUM(v2, e, o)                                   \
{                                                        \
    float p  = v2.x + v2.y;                              \
    float p1 = __shfl_down(p, 1);                        \
    float p2 = __shfl_down(p, 2);                        \
    float p3 = __shfl_down(p, 3);                        \
    float q  = __shfl_down(v2.x, 3);                     \
    e = p + p1 + p2 + q;                                 \
    o = v2.y + p1 + p2 + p3;                             \
}

#define ROW_BODY(P, I, DOEMIT)                                             \
{                                                                          \
    const int rr   = min(r0 + (I), H - 1);                                 \
    const int rofs = rr * W + cl;                                          \
    const float2 xn = *(const float2*)(Xb + rofs);                         \
    const float2 yn = *(const float2*)(Yb + rofs);                         \
    const float2 xo = rx[P];                                               \
    const float2 yo = ry[P];                                               \
    sx.x  += xn.x - xo.x;            sx.y  += xn.y - xo.y;                 \
    sy.x  += yn.x - yo.x;            sy.y  += yn.y - yo.y;                 \
    sxx.x += xn.x*xn.x - xo.x*xo.x;  sxx.y += xn.y*xn.y - xo.y*xo.y;       \
    syy.x += yn.x*yn.x - yo.x*yo.x;  syy.y += yn.y*yn.y - yo.y*yo.y;       \
    sxy.x += xn.x*yn.x - xo.x*yo.x;  sxy.y += xn.y*yn.y - xo.y*yo.y;       \
    rx[P] = xn; ry[P] = yn;                                                \
    if (DOEMIT) {                                                          \
        const int orow = r0 + (I) - 6;                                     \
        if (orow < OH) {                                                   \
            float ex, oxv, ey, oyv, exx, oxx, eyy, oyy, exy, oxy;          \
            HSUM(sx,  ex,  oxv)                                            \
            HSUM(sy,  ey,  oyv)                                            \
            HSUM(sxx, exx, oxx)                                            \
            HSUM(syy, eyy, oyy)                                            \
            HSUM(sxy, exy, oxy)                                            \
            float S0 = ssim_val(ex,  ey,  exx, eyy, exy, w0, C1, C2);      \
            float S1 = ssim_val(oxv, oyv, oxx, oyy, oxy, w0, C1, C2);      \
            acc += (v0ok ? S0 : 0.f) + (v1ok ? S1 : 0.f);                  \
        }                                                                  \
    }                                                                      \
}

__global__ __launch_bounds__(256) void ssim_slide_kernel(
    const float* __restrict__ X, const float* __restrict__ Y,
    const float* __restrict__ dr_p, const float* __restrict__ w_p,
    double* __restrict__ accum)
{
    const int t    = threadIdx.x;
    const int lane = t & 63;
    const int wave = t >> 6;

    // grid: NIMG * NGRP * 2 blocks; each block = 4 waves = 4 strips
    const int bid  = blockIdx.x;
    const int img  = bid / (NGRP * 2);
    const int rem  = bid - img * (NGRP * 2);
    const int grp  = rem >> 1;
    const int half = rem & 1;
    const int strip = half * 4 + wave;          // 0..7
    const int r0    = strip * STRIP_OUT;        // first output row of strip

    const int cbase = grp * GRPW;
    const int c0 = cbase + 2 * lane;            // even input col owned by lane
    const int cl = min(c0, W - 2);              // clamp for safe float2 load

    const float* __restrict__ Xb = X + (size_t)img * (H * W);
    const float* __restrict__ Yb = Y + (size_t)img * (H * W);

    const float dr = dr_p[0];
    const float w0 = w_p[0];                    // uniform 1/49 weight
    const float C1 = (0.01f * dr) * (0.01f * dr);
    const float C2 = (0.03f * dr) * (0.03f * dr);

    const bool v0ok = (lane <= 60) && (c0     < OW);
    const bool v1ok = (lane <= 60) && (c0 + 1 < OW);

    float2 rx[7], ry[7];
#pragma unroll
    for (int i = 0; i < 7; ++i) { rx[i] = make_float2(0.f, 0.f); ry[i] = make_float2(0.f, 0.f); }
    float2 sx  = make_float2(0.f, 0.f), sy  = make_float2(0.f, 0.f);
    float2 sxx = make_float2(0.f, 0.f), syy = make_float2(0.f, 0.f);
    float2 sxy = make_float2(0.f, 0.f);
    float acc = 0.f;

    // rows 0..6 (phases 0..6): only row 6 emits (output row r0)
    ROW_BODY(0, 0, false)
    ROW_BODY(1, 1, false)
    ROW_BODY(2, 2, false)
    ROW_BODY(3, 3, false)
    ROW_BODY(4, 4, false)
    ROW_BODY(5, 5, false)
    ROW_BODY(6, 6, true)

    // rows 7..41: 5 macro-iterations of 7 rows, all emit
    for (int j = 1; j < 6; ++j) {
        const int base = j * 7;
        ROW_BODY(0, base + 0, true)
        ROW_BODY(1, base + 1, true)
        ROW_BODY(2, base + 2, true)
        ROW_BODY(3, base + 3, true)
        ROW_BODY(4, base + 4, true)
        ROW_BODY(5, base + 5, true)
        ROW_BODY(6, base + 6, true)
    }

    // tail rows 42..47 (phases 0..5), all emit (output rows r0+36..r0+41)
    ROW_BODY(0, 42, true)
    ROW_BODY(1, 43, true)
    ROW_BODY(2, 44, true)
    ROW_BODY(3, 45, true)
    ROW_BODY(4, 46, true)
    ROW_BODY(5, 47, true)

    // wave reduce
#pragma unroll
    for (int off = 32; off > 0; off >>= 1)
        acc += __shfl_down(acc, off);

    __shared__ float wsum[4];
    if (lane == 0) wsum[wave] = acc;
    __syncthreads();
    if (t == 0) {
        float s = wsum[0] + wsum[1] + wsum[2] + wsum[3];
        atomicAdd(accum, (double)s);
    }
}

__global__ void ssim_finalize_kernel(const double* __restrict__ accum,
                                     float* __restrict__ out)
{
    const double cnt = (double)NIMG * (double)(OH * OW);
    out[0] = 1.0f - (float)(accum[0] / cnt);
}

extern "C" void kernel_launch(void* const* d_in, const int* in_sizes, int n_in,
                              void* d_out, int out_size, void* d_ws, size_t ws_size,
                              hipStream_t stream) {
    const float* X  = (const float*)d_in[0];
    const float* Y  = (const float*)d_in[1];
    const float* dr = (const float*)d_in[2];
    const float* w  = (const float*)d_in[3];
    double* accum   = (double*)d_ws;
    float* out      = (float*)d_out;

    hipMemsetAsync(accum, 0, sizeof(double), stream);

    const int nblocks = NIMG * NGRP * 2;   // 1536
    ssim_slide_kernel<<<nblocks, 256, 0, stream>>>(X, Y, dr, w, accum);
    ssim_finalize_kernel<<<1, 1, 0, stream>>>(accum, out);
}